// Round 2
// baseline (238.296 us; speedup 1.0000x reference)
//
#include <hip/hip_runtime.h>

#define NN 4096
#define IN_DIM 256
#define HID 64
#define HEADS 8

typedef __attribute__((ext_vector_type(4))) float f32x4;
typedef __attribute__((ext_vector_type(8))) short s16x8;
typedef unsigned short u16;
typedef unsigned long long u64;

__device__ inline u16 f2bf(float f) {
  union { float f; unsigned u; } v; v.f = f;
  unsigned r = (v.u + 0x7FFFu + ((v.u >> 16) & 1u)) >> 16;
  return (u16)r;
}
__device__ inline float bf2f(u16 b) {
  union { unsigned u; float f; } v; v.u = ((unsigned)b) << 16;
  return v.f;
}

// ---------------------------------------------------------------------------
// Kernel 0: detect adjacency element width (uint8 / int32 / int64).
// Probes diagonal entries at positions guaranteed zero under the other
// interpretations (byte offset %4==1 is byte#1 of an int32 0/1; odd int32
// index is the high half of an int64 0/1). All probes < 4.2MB, in-bounds
// under the smallest (uint8) layout.
// ---------------------------------------------------------------------------
__global__ void gat_detect(const void* __restrict__ adj, int* __restrict__ flag)
{
  const int lane = threadIdx.x;
  const unsigned char* a8 = (const unsigned char*)adj;
  const int* a32 = (const int*)adj;

  size_t i8 = (size_t)(4 * lane + 1) * 4097;      // diag byte if u8
  int p8 = a8[i8] != 0;

  size_t k = (size_t)(2 * lane + 1);              // odd
  int p32 = a32[k * 4097] != 0;                   // diag elem if i32
  int p64 = a32[2 * k * 4097] != 0;               // low word of diag if i64

  int ok8 = __all(p8), ok32 = __all(p32), ok64 = __all(p64);
  if (lane == 0) *flag = ok8 ? 0 : (ok32 ? 1 : (ok64 ? 2 : 1));
}

// ---------------------------------------------------------------------------
// Kernel 0b: pack adjacency into bitmask [4096 rows][64 u64 words].
// bit j of word (row*64 + jt) = adjacency[row][jt*64 + j] != 0.
// ---------------------------------------------------------------------------
__global__ __launch_bounds__(256) void gat_pack(
    const void* __restrict__ adj, const int* __restrict__ flag,
    u64* __restrict__ bits)
{
  const int mode = *flag;
  const int lane = threadIdx.x & 63;
  const int wave = (blockIdx.x * blockDim.x + threadIdx.x) >> 6;
  const int nwaves = (gridDim.x * blockDim.x) >> 6;
  const size_t nwords = (size_t)NN * NN / 64;

  for (size_t w = wave; w < nwords; w += nwaves) {
    size_t e = w * 64 + lane;
    int on;
    if (mode == 1)      on = ((const int*)adj)[e] != 0;
    else if (mode == 0) on = ((const unsigned char*)adj)[e] != 0;
    else                on = ((const long long*)adj)[e] != 0;
    u64 b = __ballot(on);
    if (lane == 0) bits[w] = b;
  }
}

// ---------------------------------------------------------------------------
// Kernel 1: H = x @ W^T  (4096 x 512), f32 out + transposed bf16 copy.
// 3-term bf16 split (hi*hi + hi*lo + lo*hi) for ~f32 accuracy via MFMA.
// ---------------------------------------------------------------------------
__global__ __launch_bounds__(256) void gat_gemm1(
    const float* __restrict__ x, const float* __restrict__ W,
    float* __restrict__ Hf, u16* __restrict__ Hbt)
{
  __shared__ u16 xhi[64 * 72], xlo[64 * 72], whi[64 * 72], wlo[64 * 72];
  const int nb = blockIdx.x;   // node block (rows)
  const int ob = blockIdx.y;   // out block  (cols) == head
  const int t = threadIdx.x;
  const int lane = t & 63, wid = t >> 6;
  const int wr = wid >> 1, wc = wid & 1;
  const int g = lane >> 4;

  f32x4 acc[2][2] = {};

  const int sn = t >> 2;          // staging row 0..63
  const int skc = (t & 3) * 16;   // staging k offset within 64-chunk

  for (int kb = 0; kb < 4; ++kb) {
    const float* xr = x + (size_t)(nb * 64 + sn) * IN_DIM + kb * 64 + skc;
    const float* wr_p = W + (size_t)(ob * 64 + sn) * IN_DIM + kb * 64 + skc;
#pragma unroll
    for (int c = 0; c < 4; ++c) {
      float4 xv = ((const float4*)xr)[c];
      float4 wv = ((const float4*)wr_p)[c];
      float xf[4] = {xv.x, xv.y, xv.z, xv.w};
      float wf[4] = {wv.x, wv.y, wv.z, wv.w};
      u16 xh[4], xl[4], wh[4], wl[4];
#pragma unroll
      for (int e = 0; e < 4; ++e) {
        xh[e] = f2bf(xf[e]); xl[e] = f2bf(xf[e] - bf2f(xh[e]));
        wh[e] = f2bf(wf[e]); wl[e] = f2bf(wf[e] - bf2f(wh[e]));
      }
      int base = sn * 72 + skc + c * 4;
      *(ushort4*)(xhi + base) = make_ushort4(xh[0], xh[1], xh[2], xh[3]);
      *(ushort4*)(xlo + base) = make_ushort4(xl[0], xl[1], xl[2], xl[3]);
      *(ushort4*)(whi + base) = make_ushort4(wh[0], wh[1], wh[2], wh[3]);
      *(ushort4*)(wlo + base) = make_ushort4(wl[0], wl[1], wl[2], wl[3]);
    }
    __syncthreads();
#pragma unroll
    for (int ks = 0; ks < 2; ++ks) {
      const int k0 = ks * 32 + g * 8;
      s16x8 ah[2], al[2], bh[2], bl[2];
#pragma unroll
      for (int nf = 0; nf < 2; ++nf) {
        int row = wr * 32 + nf * 16 + (lane & 15);
        ah[nf] = *(const s16x8*)(xhi + row * 72 + k0);
        al[nf] = *(const s16x8*)(xlo + row * 72 + k0);
      }
#pragma unroll
      for (int of = 0; of < 2; ++of) {
        int row = wc * 32 + of * 16 + (lane & 15);
        bh[of] = *(const s16x8*)(whi + row * 72 + k0);
        bl[of] = *(const s16x8*)(wlo + row * 72 + k0);
      }
#pragma unroll
      for (int nf = 0; nf < 2; ++nf)
#pragma unroll
        for (int of = 0; of < 2; ++of) {
          acc[nf][of] = __builtin_amdgcn_mfma_f32_16x16x32_bf16(ah[nf], bh[of], acc[nf][of], 0, 0, 0);
          acc[nf][of] = __builtin_amdgcn_mfma_f32_16x16x32_bf16(ah[nf], bl[of], acc[nf][of], 0, 0, 0);
          acc[nf][of] = __builtin_amdgcn_mfma_f32_16x16x32_bf16(al[nf], bh[of], acc[nf][of], 0, 0, 0);
        }
    }
    __syncthreads();
  }

  // epilogue: f32 H + transposed bf16 copy (via LDS, reuse xhi)
#pragma unroll
  for (int nf = 0; nf < 2; ++nf)
#pragma unroll
    for (int of = 0; of < 2; ++of)
#pragma unroll
      for (int r = 0; r < 4; ++r) {
        int nloc = wr * 32 + nf * 16 + g * 4 + r;
        int oloc = wc * 32 + of * 16 + (lane & 15);
        Hf[(size_t)(nb * 64 + nloc) * 512 + ob * 64 + oloc] = acc[nf][of][r];
      }
  u16* Ct = xhi;  // [64 o][72 n]
#pragma unroll
  for (int nf = 0; nf < 2; ++nf)
#pragma unroll
    for (int of = 0; of < 2; ++of)
#pragma unroll
      for (int r = 0; r < 4; ++r) {
        int nloc = wr * 32 + nf * 16 + g * 4 + r;
        int oloc = wc * 32 + of * 16 + (lane & 15);
        Ct[oloc * 72 + nloc] = f2bf(acc[nf][of][r]);
      }
  __syncthreads();
  {
    int o = t >> 2, nc = (t & 3) * 16;
#pragma unroll
    for (int c = 0; c < 2; ++c) {
      s16x8 v = *(const s16x8*)(Ct + o * 72 + nc + c * 8);
      *(s16x8*)(Hbt + (size_t)(ob * 64 + o) * NN + nb * 64 + nc + c * 8) = v;
    }
  }
}

// ---------------------------------------------------------------------------
// Kernel 2: src/dst attention scores. One wave per node.
// ---------------------------------------------------------------------------
__global__ __launch_bounds__(256) void gat_scores(
    const float* __restrict__ Hf, const float* __restrict__ a_src,
    const float* __restrict__ a_dst, float* __restrict__ s_src,
    float* __restrict__ s_dst)
{
  int node = blockIdx.x * 4 + (threadIdx.x >> 6);
  int lane = threadIdx.x & 63;
  int h = lane >> 3, c = lane & 7;
  const float* hrow = Hf + (size_t)node * 512 + h * 64 + c * 8;
  const float* as = a_src + h * 64 + c * 8;
  const float* ad = a_dst + h * 64 + c * 8;
  float vs = 0.f, vd = 0.f;
#pragma unroll
  for (int e = 0; e < 8; ++e) { float hv = hrow[e]; vs += hv * as[e]; vd += hv * ad[e]; }
#pragma unroll
  for (int m = 1; m < 8; m <<= 1) { vs += __shfl_xor(vs, m); vd += __shfl_xor(vd, m); }
  if (c == 0) { s_src[node * 8 + h] = vs; s_dst[node * 8 + h] = vd; }
}

// ---------------------------------------------------------------------------
// Kernel 3: flash-GAT. 256 blocks x 512 threads; block = 16 i-rows, wave = head.
// out^T[f][i] = sum_j Hbt[h][f][j] * P^T[j][i] via 16x16x32 bf16 MFMA,
// online softmax over j in tiles of 64. Mask comes from the packed bitmask.
// ---------------------------------------------------------------------------
__global__ __launch_bounds__(512) void gat_flash(
    const u64* __restrict__ bits, const u16* __restrict__ Hbt,
    const float* __restrict__ s_src, const float* __restrict__ s_dst,
    float* __restrict__ out)
{
  __shared__ u64 bitw[16];
  __shared__ float dsc[512];               // [j within tile][h]
  __shared__ float hstage[8 * 16 * 64];

  const int t = threadIdx.x, lane = t & 63, h = t >> 6;
  const int blk = blockIdx.x;
  const int i_loc = lane & 15;
  const int g = lane >> 4;
  const int j0 = g * 8;

  const float s_i = s_src[(size_t)(blk * 16 + i_loc) * 8 + h];
  const u16* hb = Hbt + (size_t)(h * 64 + i_loc) * NN + j0;

  f32x4 acc[4] = {};
  float m_run = -INFINITY, l_run = 0.f;

  for (int jt = 0; jt < 64; ++jt) {
    // issue A-fragment global loads early (no LDS dependency)
    s16x8 afr[4][2];
#pragma unroll
    for (int fb = 0; fb < 4; ++fb) {
      const u16* p = hb + (size_t)fb * 16 * NN + jt * 64;
      afr[fb][0] = *(const s16x8*)(p);
      afr[fb][1] = *(const s16x8*)(p + 32);
    }
    __syncthreads();
    if (t < 16) bitw[t] = bits[(size_t)(blk * 16 + t) * 64 + jt];
    dsc[t] = s_dst[(size_t)jt * 512 + t];
    __syncthreads();

    const u64 am = bitw[i_loc];
    float pv[16];
    float m_new = m_run;
#pragma unroll
    for (int half = 0; half < 2; ++half) {
      unsigned int amh = (unsigned int)(am >> (half * 32 + j0));
#pragma unroll
      for (int tt = 0; tt < 8; ++tt) {
        float d = dsc[(half * 32 + j0 + tt) * 8 + h];
        float z = s_i + d;
        z = z > 0.f ? z : 0.2f * z;
        bool on = ((amh >> tt) & 1u) != 0;
        z = on ? z : -10000.f;
        pv[half * 8 + tt] = z;
        m_new = fmaxf(m_new, z);
      }
    }
    m_new = fmaxf(m_new, __shfl_xor(m_new, 16));
    m_new = fmaxf(m_new, __shfl_xor(m_new, 32));
    float scale = __expf(m_run - m_new);
    float lsum = 0.f;
#pragma unroll
    for (int tt = 0; tt < 16; ++tt) { pv[tt] = __expf(pv[tt] - m_new); lsum += pv[tt]; }
    lsum += __shfl_xor(lsum, 16);
    lsum += __shfl_xor(lsum, 32);
    l_run = l_run * scale + lsum;
    m_run = m_new;

    s16x8 pb0, pb1;
#pragma unroll
    for (int tt = 0; tt < 8; ++tt) {
      pb0[tt] = (short)f2bf(pv[tt]);
      pb1[tt] = (short)f2bf(pv[8 + tt]);
    }
#pragma unroll
    for (int fb = 0; fb < 4; ++fb) {
      acc[fb][0] *= scale; acc[fb][1] *= scale;
      acc[fb][2] *= scale; acc[fb][3] *= scale;
      acc[fb] = __builtin_amdgcn_mfma_f32_16x16x32_bf16(afr[fb][0], pb0, acc[fb], 0, 0, 0);
      acc[fb] = __builtin_amdgcn_mfma_f32_16x16x32_bf16(afr[fb][1], pb1, acc[fb], 0, 0, 0);
    }
  }

  float inv_l = 1.f / l_run;
#pragma unroll
  for (int fb = 0; fb < 4; ++fb)
#pragma unroll
    for (int r = 0; r < 4; ++r) {
      int f = fb * 16 + g * 4 + r;
      hstage[h * 1024 + i_loc * 64 + f] = acc[fb][r] * inv_l;
    }
  __syncthreads();
#pragma unroll
  for (int e = t; e < 1024; e += 512) {
    float s = 0.f;
#pragma unroll
    for (int w = 0; w < 8; ++w) s += hstage[w * 1024 + e];
    out[(size_t)blk * 1024 + e] = s * 0.125f;
  }
}

extern "C" void kernel_launch(void* const* d_in, const int* in_sizes, int n_in,
                              void* d_out, int out_size, void* d_ws, size_t ws_size,
                              hipStream_t stream)
{
  const float* x = (const float*)d_in[0];
  const void* adj = d_in[1];
  const float* W = (const float*)d_in[2];
  const float* a_src = (const float*)d_in[3];
  const float* a_dst = (const float*)d_in[4];
  float* out = (float*)d_out;

  char* ws = (char*)d_ws;
  float* Hf = (float*)ws;                                   // 8 MB
  u16* Hbt = (u16*)(ws + 8 * 1024 * 1024);                  // 4 MB  [8][64][4096] bf16
  float* s_src = (float*)(ws + 12 * 1024 * 1024);           // 128 KB
  float* s_dst = (float*)(ws + 12 * 1024 * 1024 + 128 * 1024);
  int* flag = (int*)(ws + 12 * 1024 * 1024 + 256 * 1024);
  u64* bits = (u64*)(ws + 12 * 1024 * 1024 + 512 * 1024);   // 2 MB

  gat_detect<<<1, 64, 0, stream>>>(adj, flag);
  gat_pack<<<2048, 256, 0, stream>>>(adj, flag, bits);
  gat_gemm1<<<dim3(64, 8), 256, 0, stream>>>(x, W, Hf, Hbt);
  gat_scores<<<1024, 256, 0, stream>>>(Hf, a_src, a_dst, s_src, s_dst);
  gat_flash<<<256, 512, 0, stream>>>(bits, Hbt, s_src, s_dst, out);
}

// Round 3
// 184.744 us; speedup vs baseline: 1.2899x; 1.2899x over previous
//
#include <hip/hip_runtime.h>

#define NN 4096
#define IN_DIM 256
#define HID 64
#define HEADS 8

typedef __attribute__((ext_vector_type(4))) float f32x4;
typedef __attribute__((ext_vector_type(8))) short s16x8;
typedef unsigned short u16;
typedef unsigned long long u64;

__device__ inline u16 f2bf(float f) {
  union { float f; unsigned u; } v; v.f = f;
  unsigned r = (v.u + 0x7FFFu + ((v.u >> 16) & 1u)) >> 16;
  return (u16)r;
}
__device__ inline float bf2f(u16 b) {
  union { unsigned u; float f; } v; v.u = ((unsigned)b) << 16;
  return v.f;
}

// ---------------------------------------------------------------------------
// Kernel 0: detect adjacency element width (uint8 / int32 / int64).
// ---------------------------------------------------------------------------
__global__ void gat_detect(const void* __restrict__ adj, int* __restrict__ flag)
{
  const int lane = threadIdx.x;
  const unsigned char* a8 = (const unsigned char*)adj;
  const int* a32 = (const int*)adj;

  size_t i8 = (size_t)(4 * lane + 1) * 4097;      // diag byte if u8
  int p8 = a8[i8] != 0;

  size_t k = (size_t)(2 * lane + 1);              // odd
  int p32 = a32[k * 4097] != 0;                   // diag elem if i32
  int p64 = a32[2 * k * 4097] != 0;               // low word of diag if i64

  int ok8 = __all(p8), ok32 = __all(p32), ok64 = __all(p64);
  if (lane == 0) *flag = ok8 ? 0 : (ok32 ? 1 : (ok64 ? 2 : 1));
}

// ---------------------------------------------------------------------------
// Kernel 0b: pack adjacency into bitmask [4096 rows][64 u64 words].
// ---------------------------------------------------------------------------
__global__ __launch_bounds__(256) void gat_pack(
    const void* __restrict__ adj, const int* __restrict__ flag,
    u64* __restrict__ bits)
{
  const int mode = *flag;
  const int lane = threadIdx.x & 63;
  const int wave = (blockIdx.x * blockDim.x + threadIdx.x) >> 6;
  const int nwaves = (gridDim.x * blockDim.x) >> 6;
  const size_t nwords = (size_t)NN * NN / 64;

  for (size_t w = wave; w < nwords; w += nwaves) {
    size_t e = w * 64 + lane;
    int on;
    if (mode == 1)      on = ((const int*)adj)[e] != 0;
    else if (mode == 0) on = ((const unsigned char*)adj)[e] != 0;
    else                on = ((const long long*)adj)[e] != 0;
    u64 b = __ballot(on);
    if (lane == 0) bits[w] = b;
  }
}

// ---------------------------------------------------------------------------
// Kernel 1: H = x @ W^T  (4096 x 512), f32 out + transposed bf16 copy.
// 3-term bf16 split (hi*hi + hi*lo + lo*hi) for ~f32 accuracy via MFMA.
// ---------------------------------------------------------------------------
__global__ __launch_bounds__(256) void gat_gemm1(
    const float* __restrict__ x, const float* __restrict__ W,
    float* __restrict__ Hf, u16* __restrict__ Hbt)
{
  __shared__ u16 xhi[64 * 72], xlo[64 * 72], whi[64 * 72], wlo[64 * 72];
  const int nb = blockIdx.x;   // node block (rows)
  const int ob = blockIdx.y;   // out block  (cols) == head
  const int t = threadIdx.x;
  const int lane = t & 63, wid = t >> 6;
  const int wr = wid >> 1, wc = wid & 1;
  const int g = lane >> 4;

  f32x4 acc[2][2] = {};

  const int sn = t >> 2;          // staging row 0..63
  const int skc = (t & 3) * 16;   // staging k offset within 64-chunk

  for (int kb = 0; kb < 4; ++kb) {
    const float* xr = x + (size_t)(nb * 64 + sn) * IN_DIM + kb * 64 + skc;
    const float* wr_p = W + (size_t)(ob * 64 + sn) * IN_DIM + kb * 64 + skc;
#pragma unroll
    for (int c = 0; c < 4; ++c) {
      float4 xv = ((const float4*)xr)[c];
      float4 wv = ((const float4*)wr_p)[c];
      float xf[4] = {xv.x, xv.y, xv.z, xv.w};
      float wf[4] = {wv.x, wv.y, wv.z, wv.w};
      u16 xh[4], xl[4], wh[4], wl[4];
#pragma unroll
      for (int e = 0; e < 4; ++e) {
        xh[e] = f2bf(xf[e]); xl[e] = f2bf(xf[e] - bf2f(xh[e]));
        wh[e] = f2bf(wf[e]); wl[e] = f2bf(wf[e] - bf2f(wh[e]));
      }
      int base = sn * 72 + skc + c * 4;
      *(ushort4*)(xhi + base) = make_ushort4(xh[0], xh[1], xh[2], xh[3]);
      *(ushort4*)(xlo + base) = make_ushort4(xl[0], xl[1], xl[2], xl[3]);
      *(ushort4*)(whi + base) = make_ushort4(wh[0], wh[1], wh[2], wh[3]);
      *(ushort4*)(wlo + base) = make_ushort4(wl[0], wl[1], wl[2], wl[3]);
    }
    __syncthreads();
#pragma unroll
    for (int ks = 0; ks < 2; ++ks) {
      const int k0 = ks * 32 + g * 8;
      s16x8 ah[2], al[2], bh[2], bl[2];
#pragma unroll
      for (int nf = 0; nf < 2; ++nf) {
        int row = wr * 32 + nf * 16 + (lane & 15);
        ah[nf] = *(const s16x8*)(xhi + row * 72 + k0);
        al[nf] = *(const s16x8*)(xlo + row * 72 + k0);
      }
#pragma unroll
      for (int of = 0; of < 2; ++of) {
        int row = wc * 32 + of * 16 + (lane & 15);
        bh[of] = *(const s16x8*)(whi + row * 72 + k0);
        bl[of] = *(const s16x8*)(wlo + row * 72 + k0);
      }
#pragma unroll
      for (int nf = 0; nf < 2; ++nf)
#pragma unroll
        for (int of = 0; of < 2; ++of) {
          acc[nf][of] = __builtin_amdgcn_mfma_f32_16x16x32_bf16(ah[nf], bh[of], acc[nf][of], 0, 0, 0);
          acc[nf][of] = __builtin_amdgcn_mfma_f32_16x16x32_bf16(ah[nf], bl[of], acc[nf][of], 0, 0, 0);
          acc[nf][of] = __builtin_amdgcn_mfma_f32_16x16x32_bf16(al[nf], bh[of], acc[nf][of], 0, 0, 0);
        }
    }
    __syncthreads();
  }

  // epilogue: f32 H + transposed bf16 copy (via LDS, reuse xhi)
#pragma unroll
  for (int nf = 0; nf < 2; ++nf)
#pragma unroll
    for (int of = 0; of < 2; ++of)
#pragma unroll
      for (int r = 0; r < 4; ++r) {
        int nloc = wr * 32 + nf * 16 + g * 4 + r;
        int oloc = wc * 32 + of * 16 + (lane & 15);
        Hf[(size_t)(nb * 64 + nloc) * 512 + ob * 64 + oloc] = acc[nf][of][r];
      }
  u16* Ct = xhi;  // [64 o][72 n]
#pragma unroll
  for (int nf = 0; nf < 2; ++nf)
#pragma unroll
    for (int of = 0; of < 2; ++of)
#pragma unroll
      for (int r = 0; r < 4; ++r) {
        int nloc = wr * 32 + nf * 16 + g * 4 + r;
        int oloc = wc * 32 + of * 16 + (lane & 15);
        Ct[oloc * 72 + nloc] = f2bf(acc[nf][of][r]);
      }
  __syncthreads();
  {
    int o = t >> 2, nc = (t & 3) * 16;
#pragma unroll
    for (int c = 0; c < 2; ++c) {
      s16x8 v = *(const s16x8*)(Ct + o * 72 + nc + c * 8);
      *(s16x8*)(Hbt + (size_t)(ob * 64 + o) * NN + nb * 64 + nc + c * 8) = v;
    }
  }
}

// ---------------------------------------------------------------------------
// Kernel 2: src/dst attention scores -> transposed layout [h][node].
// ---------------------------------------------------------------------------
__global__ __launch_bounds__(256) void gat_scores(
    const float* __restrict__ Hf, const float* __restrict__ a_src,
    const float* __restrict__ a_dst, float* __restrict__ s_srcT,
    float* __restrict__ s_dstT)
{
  int node = blockIdx.x * 4 + (threadIdx.x >> 6);
  int lane = threadIdx.x & 63;
  int h = lane >> 3, c = lane & 7;
  const float* hrow = Hf + (size_t)node * 512 + h * 64 + c * 8;
  const float* as = a_src + h * 64 + c * 8;
  const float* ad = a_dst + h * 64 + c * 8;
  float vs = 0.f, vd = 0.f;
#pragma unroll
  for (int e = 0; e < 8; ++e) { float hv = hrow[e]; vs += hv * as[e]; vd += hv * ad[e]; }
#pragma unroll
  for (int m = 1; m < 8; m <<= 1) { vs += __shfl_xor(vs, m); vd += __shfl_xor(vd, m); }
  if (c == 0) { s_srcT[h * NN + node] = vs; s_dstT[h * NN + node] = vd; }
}

// ---------------------------------------------------------------------------
// Kernel 3: flash-GAT, barrier-free main loop.
// 1024 threads = 16 waves = 8 heads x 2 j-halves; block = 16 i-rows.
// Each wave: 32 j-tiles of 64, online softmax fully in registers, direct
// L2 loads (no LDS staging). Epilogue: js-merge + head-mean in LDS.
// ---------------------------------------------------------------------------
__global__ __launch_bounds__(1024) void gat_flash(
    const u64* __restrict__ bits, const u16* __restrict__ Hbt,
    const float* __restrict__ s_srcT, const float* __restrict__ s_dstT,
    float* __restrict__ out)
{
  __shared__ float Abuf[8][16][66];   // padded: bank = (2i + f) & 31, conflict-free
  __shared__ float Mbuf[8][16][2];

  const int t = threadIdx.x, lane = t & 63, w = t >> 6;
  const int h = w & 7, jsw = w >> 3;
  const int blk = blockIdx.x;
  const int i_loc = lane & 15, g = lane >> 4, j0 = g * 8;

  const float s_i = s_srcT[(size_t)h * NN + blk * 16 + i_loc];
  const u16* hb = Hbt + (size_t)(h * 64 + i_loc) * NN;
  const float* dT = s_dstT + (size_t)h * NN;
  const u64* brow = bits + (size_t)(blk * 16 + i_loc) * 64;

  f32x4 acc[4] = {};
  float m_run = -INFINITY, l_run = 0.f;

  const int jt0 = jsw * 32, jt1 = jt0 + 32;
  u64 am_n = brow[jt0];
  f32x4 d_n[4];
  d_n[0] = *(const f32x4*)(dT + jt0 * 64 + j0);
  d_n[1] = *(const f32x4*)(dT + jt0 * 64 + j0 + 4);
  d_n[2] = *(const f32x4*)(dT + jt0 * 64 + 32 + j0);
  d_n[3] = *(const f32x4*)(dT + jt0 * 64 + 32 + j0 + 4);

  for (int jt = jt0; jt < jt1; ++jt) {
    // A-fragment loads: issued now, consumed after softmax (latency hidden)
    s16x8 afr[4][2];
    const u16* p = hb + jt * 64 + j0;
#pragma unroll
    for (int fb = 0; fb < 4; ++fb) {
      afr[fb][0] = *(const s16x8*)(p + (size_t)fb * 16 * NN);
      afr[fb][1] = *(const s16x8*)(p + (size_t)fb * 16 * NN + 32);
    }

    const u64 am = am_n;
    f32x4 d0 = d_n[0], d1 = d_n[1], d2 = d_n[2], d3 = d_n[3];
    // prefetch next tile's mask word + dst scores (uniform, no divergence)
    {
      int jn = jt + 1 < jt1 ? jt + 1 : jt1 - 1;
      am_n = brow[jn];
      d_n[0] = *(const f32x4*)(dT + jn * 64 + j0);
      d_n[1] = *(const f32x4*)(dT + jn * 64 + j0 + 4);
      d_n[2] = *(const f32x4*)(dT + jn * 64 + 32 + j0);
      d_n[3] = *(const f32x4*)(dT + jn * 64 + 32 + j0 + 4);
    }

    const unsigned amlo = (unsigned)(am >> j0);          // bits for j0..j0+7
    const unsigned amhi = (unsigned)(am >> (32 + j0));   // bits for 32+j0..+7

    float pv[16];
    float m_new = m_run;
#pragma unroll
    for (int q = 0; q < 4; ++q) {
      float z = s_i + d0[q]; z = fmaxf(z, 0.2f * z);
      z = ((amlo >> q) & 1u) ? z : -10000.f;
      pv[q] = z; m_new = fmaxf(m_new, z);
    }
#pragma unroll
    for (int q = 0; q < 4; ++q) {
      float z = s_i + d1[q]; z = fmaxf(z, 0.2f * z);
      z = ((amlo >> (4 + q)) & 1u) ? z : -10000.f;
      pv[4 + q] = z; m_new = fmaxf(m_new, z);
    }
#pragma unroll
    for (int q = 0; q < 4; ++q) {
      float z = s_i + d2[q]; z = fmaxf(z, 0.2f * z);
      z = ((amhi >> q) & 1u) ? z : -10000.f;
      pv[8 + q] = z; m_new = fmaxf(m_new, z);
    }
#pragma unroll
    for (int q = 0; q < 4; ++q) {
      float z = s_i + d3[q]; z = fmaxf(z, 0.2f * z);
      z = ((amhi >> (4 + q)) & 1u) ? z : -10000.f;
      pv[12 + q] = z; m_new = fmaxf(m_new, z);
    }
    m_new = fmaxf(m_new, __shfl_xor(m_new, 16));
    m_new = fmaxf(m_new, __shfl_xor(m_new, 32));

    float scale = __expf(m_run - m_new);
    float lsum = 0.f;
#pragma unroll
    for (int tt = 0; tt < 16; ++tt) { pv[tt] = __expf(pv[tt] - m_new); lsum += pv[tt]; }
    lsum += __shfl_xor(lsum, 16);
    lsum += __shfl_xor(lsum, 32);
    l_run = l_run * scale + lsum;
    m_run = m_new;

    s16x8 pb0, pb1;
#pragma unroll
    for (int tt = 0; tt < 8; ++tt) {
      pb0[tt] = (short)f2bf(pv[tt]);
      pb1[tt] = (short)f2bf(pv[8 + tt]);
    }
#pragma unroll
    for (int fb = 0; fb < 4; ++fb) {
      acc[fb][0] *= scale; acc[fb][1] *= scale;
      acc[fb][2] *= scale; acc[fb][3] *= scale;
      acc[fb] = __builtin_amdgcn_mfma_f32_16x16x32_bf16(afr[fb][0], pb0, acc[fb], 0, 0, 0);
      acc[fb] = __builtin_amdgcn_mfma_f32_16x16x32_bf16(afr[fb][1], pb1, acc[fb], 0, 0, 0);
    }
  }

  // epilogue: merge the two j-halves per head, then mean over heads
  if (jsw == 1) {
#pragma unroll
    for (int fb = 0; fb < 4; ++fb)
#pragma unroll
      for (int r = 0; r < 4; ++r)
        Abuf[h][i_loc][fb * 16 + g * 4 + r] = acc[fb][r];
    if (g == 0) { Mbuf[h][i_loc][0] = m_run; Mbuf[h][i_loc][1] = l_run; }
  }
  __syncthreads();
  if (jsw == 0) {
    float m1 = Mbuf[h][i_loc][0], l1 = Mbuf[h][i_loc][1];
    float M = fmaxf(m_run, m1);
    float w0 = __expf(m_run - M), w1 = __expf(m1 - M);
    float invL = 1.f / (w0 * l_run + w1 * l1);
#pragma unroll
    for (int fb = 0; fb < 4; ++fb)
#pragma unroll
      for (int r = 0; r < 4; ++r) {
        int f = fb * 16 + g * 4 + r;
        float a1 = Abuf[h][i_loc][f];
        Abuf[h][i_loc][f] = (w0 * acc[fb][r] + w1 * a1) * invL;
      }
  }
  __syncthreads();
  {
    int i = t >> 6, f = t & 63;
    float s = 0.f;
#pragma unroll
    for (int hh = 0; hh < 8; ++hh) s += Abuf[hh][i][f];
    out[(size_t)(blk * 16 + i) * 64 + f] = s * 0.125f;
  }
}

extern "C" void kernel_launch(void* const* d_in, const int* in_sizes, int n_in,
                              void* d_out, int out_size, void* d_ws, size_t ws_size,
                              hipStream_t stream)
{
  const float* x = (const float*)d_in[0];
  const void* adj = d_in[1];
  const float* W = (const float*)d_in[2];
  const float* a_src = (const float*)d_in[3];
  const float* a_dst = (const float*)d_in[4];
  float* out = (float*)d_out;

  char* ws = (char*)d_ws;
  float* Hf = (float*)ws;                                   // 8 MB
  u16* Hbt = (u16*)(ws + 8 * 1024 * 1024);                  // 4 MB  [8][64][4096] bf16
  float* s_srcT = (float*)(ws + 12 * 1024 * 1024);          // 128 KB [8][4096]
  float* s_dstT = (float*)(ws + 12 * 1024 * 1024 + 128 * 1024);
  int* flag = (int*)(ws + 12 * 1024 * 1024 + 256 * 1024);
  u64* bits = (u64*)(ws + 12 * 1024 * 1024 + 512 * 1024);   // 2 MB

  gat_detect<<<1, 64, 0, stream>>>(adj, flag);
  gat_pack<<<2048, 256, 0, stream>>>(adj, flag, bits);
  gat_gemm1<<<dim3(64, 8), 256, 0, stream>>>(x, W, Hf, Hbt);
  gat_scores<<<1024, 256, 0, stream>>>(Hf, a_src, a_dst, s_srcT, s_dstT);
  gat_flash<<<256, 1024, 0, stream>>>(bits, Hbt, s_srcT, s_dstT, out);
}